// Round 1
// baseline (19376.497 us; speedup 1.0000x reference)
//
#include <hip/hip_runtime.h>

// Problem dims (fixed by setup_inputs): T=256, B=64, I=512, H=2048
#define T_DIM 256
#define B_DIM 64
#define I_DIM 512
#define H_DIM 2048
#define BH (B_DIM * H_DIM)      // 131072 floats per timestep slice
#define NBLK 256                // persistent-kernel grid (1 block per CU)
#define KSPLIT 32               // k-splits in recurrent GEMM (k-range 64)
#define NSLICE 8                // n-blocks (n-range 256)

// =====================================================================
// Kernel A: xin[m,n] = sum_k x[m,k] * W_ih[n,k] + b_ih[n] + b_hh[n]
// M = T*B = 16384, K = 512, N = 2048.  Tile 128x128, BK=16, 8x8/thread.
// Writes into d_out[0 : T*B*H] (out slice t doubles as xin_t storage).
// =====================================================================
__global__ __launch_bounds__(256) void xin_gemm(
    const float* __restrict__ x, const float* __restrict__ Wih,
    const float* __restrict__ bih, const float* __restrict__ bhh,
    float* __restrict__ out)
{
  __shared__ __align__(16) float As[16][132];  // k-major, pad->16B-aligned rows
  __shared__ __align__(16) float Bs[16][132];
  const int tid = threadIdx.x;
  const int nb = blockIdx.x & 15, mb = blockIdx.x >> 4;
  const int m0 = mb * 128, n0 = nb * 128;
  const int tx = tid & 15, ty = tid >> 4;   // tx: n-group (16), ty: m-group (16)

  float acc[8][8];
  #pragma unroll
  for (int i = 0; i < 8; ++i)
    #pragma unroll
    for (int j = 0; j < 8; ++j) acc[i][j] = 0.f;

  for (int k0 = 0; k0 < I_DIM; k0 += 16) {
    __syncthreads();
    // stage x-tile and W-tile transposed to k-major
    {
      const int r = tid >> 1;
      #pragma unroll
      for (int c = 0; c < 2; ++c) {
        const int kq = (tid & 1) * 4 + c * 8;
        float4 va = *(const float4*)&x[(size_t)(m0 + r) * I_DIM + k0 + kq];
        As[kq + 0][r] = va.x; As[kq + 1][r] = va.y;
        As[kq + 2][r] = va.z; As[kq + 3][r] = va.w;
        float4 vb = *(const float4*)&Wih[(size_t)(n0 + r) * I_DIM + k0 + kq];
        Bs[kq + 0][r] = vb.x; Bs[kq + 1][r] = vb.y;
        Bs[kq + 2][r] = vb.z; Bs[kq + 3][r] = vb.w;
      }
    }
    __syncthreads();
    #pragma unroll 4
    for (int k = 0; k < 16; ++k) {
      float a[8], b[8];
      *(float4*)&a[0] = *(const float4*)&As[k][ty * 8];
      *(float4*)&a[4] = *(const float4*)&As[k][ty * 8 + 4];
      *(float4*)&b[0] = *(const float4*)&Bs[k][tx * 4];        // n-tile lo half
      *(float4*)&b[4] = *(const float4*)&Bs[k][64 + tx * 4];   // n-tile hi half
      #pragma unroll
      for (int i = 0; i < 8; ++i)
        #pragma unroll
        for (int j = 0; j < 8; ++j) acc[i][j] += a[i] * b[j];
    }
  }

  // epilogue: + (b_ih + b_hh), store
  float bb[8];
  #pragma unroll
  for (int j = 0; j < 4; ++j) {
    bb[j]     = bih[n0 + tx * 4 + j]      + bhh[n0 + tx * 4 + j];
    bb[4 + j] = bih[n0 + 64 + tx * 4 + j] + bhh[n0 + 64 + tx * 4 + j];
  }
  #pragma unroll
  for (int i = 0; i < 8; ++i) {
    const size_t m = (size_t)(m0 + ty * 8 + i);
    float4 v0 = make_float4(acc[i][0] + bb[0], acc[i][1] + bb[1],
                            acc[i][2] + bb[2], acc[i][3] + bb[3]);
    float4 v1 = make_float4(acc[i][4] + bb[4], acc[i][5] + bb[5],
                            acc[i][6] + bb[6], acc[i][7] + bb[7]);
    *(float4*)&out[m * H_DIM + n0 + tx * 4]      = v0;
    *(float4*)&out[m * H_DIM + n0 + 64 + tx * 4] = v1;
  }
}

// =====================================================================
// Grid barrier: two-level (8 groups of 32 blocks), monotonic phase.
// Counters live in d_ws[0:4096], zeroed by hipMemsetAsync each launch.
// =====================================================================
__device__ inline void gbarrier(unsigned* bar, unsigned ph, int bid) {
  __syncthreads();
  if (threadIdx.x == 0) {
    unsigned* flag = bar;                       // [0]
    unsigned* mcnt = bar + 16;                  // 64B offset
    unsigned* gcnt = bar + 32 + (bid >> 5) * 32;// 128B apart per group
    unsigned prev = __hip_atomic_fetch_add(gcnt, 1u, __ATOMIC_ACQ_REL,
                                           __HIP_MEMORY_SCOPE_AGENT);
    if (prev == 32u * ph - 1u) {                // group finisher
      unsigned mprev = __hip_atomic_fetch_add(mcnt, 1u, __ATOMIC_ACQ_REL,
                                              __HIP_MEMORY_SCOPE_AGENT);
      if (mprev == 8u * ph - 1u)
        __hip_atomic_store(flag, ph, __ATOMIC_RELEASE,
                           __HIP_MEMORY_SCOPE_AGENT);
    }
    while (__hip_atomic_load(flag, __ATOMIC_ACQUIRE,
                             __HIP_MEMORY_SCOPE_AGENT) < ph)
      __builtin_amdgcn_s_sleep(1);
  }
  __syncthreads();
}

// =====================================================================
// Kernel B: persistent scan.  grid = 256 blocks x 256 thr, 1 block/CU.
// Block (nb, ks): nb = n-slice of 256 cols, ks = k-split of 64.
// W_hh slice (256n x 64k) lives in LDS for all 256 steps.
// Step t: phaseA: partial[ks][b][n] = sum_{k in ks} h[t-1][b,k]*W[n,k]
//         barrier
//         phaseB: h[t] = 0.99*h[t-1] + 0.01*relu(xin + sum_ks partial)
//         barrier
// h history lives in d_out (in-place over xin).
// =====================================================================
__global__ __launch_bounds__(256) void ctrnn_scan(
    const float* __restrict__ Whh, float* out,
    float* __restrict__ partial, unsigned* bar)
{
  __shared__ __align__(16) float Ws[64][260];  // [k][n], pad 4 (16B rows)
  __shared__ __align__(16) float hs[64][68];   // [k][b], pad 4

  const int tid = threadIdx.x;
  const int bid = blockIdx.x;
  const int nb = bid & (NSLICE - 1);    // 0..7
  const int ks = bid >> 3;              // 0..31
  const int n0 = nb * 256, k0 = ks * 64;
  const int tn = tid & 31, tb = tid >> 5;  // tn: n-group(32), tb: b-group(8)

  // ---- load W_hh slice once: W[n0+n][k0+k] -> Ws[k][n] ----
  #pragma unroll
  for (int pass = 0; pass < 16; ++pass) {
    const int n  = (tid >> 2) + (pass & 3) * 64;
    const int kq = (tid & 3) * 4 + (pass >> 2) * 16;
    float4 w = *(const float4*)&Whh[(size_t)(n0 + n) * H_DIM + k0 + kq];
    Ws[kq + 0][n] = w.x; Ws[kq + 1][n] = w.y;
    Ws[kq + 2][n] = w.z; Ws[kq + 3][n] = w.w;
  }
  __syncthreads();

  unsigned phase = 0;
  for (int t = 0; t < T_DIM; ++t) {
    // -------- phase A: partial GEMM (skip at t=0, h_{-1}=0) --------
    if (t > 0) {
      const float* hprev = out + (size_t)(t - 1) * BH;
      #pragma unroll
      for (int c = 0; c < 4; ++c) {              // stage h -> hs[k][b]
        const int b  = tid >> 2;
        const int kq = (tid & 3) * 4 + c * 16;
        float4 h4 = *(const float4*)&hprev[(size_t)b * H_DIM + k0 + kq];
        hs[kq + 0][b] = h4.x; hs[kq + 1][b] = h4.y;
        hs[kq + 2][b] = h4.z; hs[kq + 3][b] = h4.w;
      }
      __syncthreads();

      float acc[8][8];
      #pragma unroll
      for (int i = 0; i < 8; ++i)
        #pragma unroll
        for (int j = 0; j < 8; ++j) acc[i][j] = 0.f;

      #pragma unroll 4
      for (int k = 0; k < 64; ++k) {
        float a[8], w[8];
        *(float4*)&a[0] = *(const float4*)&hs[k][tb * 8];
        *(float4*)&a[4] = *(const float4*)&hs[k][tb * 8 + 4];
        *(float4*)&w[0] = *(const float4*)&Ws[k][tn * 4];        // n lo half
        *(float4*)&w[4] = *(const float4*)&Ws[k][128 + tn * 4];  // n hi half
        #pragma unroll
        for (int i = 0; i < 8; ++i)
          #pragma unroll
          for (int j = 0; j < 8; ++j) acc[i][j] += a[i] * w[j];
      }

      float* pp = partial + (size_t)ks * BH;
      #pragma unroll
      for (int i = 0; i < 8; ++i) {
        const size_t b = (size_t)(tb * 8 + i);
        *(float4*)&pp[b * H_DIM + n0 + tn * 4] =
            make_float4(acc[i][0], acc[i][1], acc[i][2], acc[i][3]);
        *(float4*)&pp[b * H_DIM + n0 + 128 + tn * 4] =
            make_float4(acc[i][4], acc[i][5], acc[i][6], acc[i][7]);
      }
      __syncthreads();   // hs safe to rewrite next step after barriers anyway
    }
    gbarrier(bar, ++phase, bid);

    // -------- phase B: reduce + leaky-relu update (in place) --------
    {
      const size_t o = (size_t)bid * 512 + (size_t)tid * 2;
      float s0 = 0.f, s1 = 0.f, s2 = 0.f, s3 = 0.f;
      float t0 = 0.f, t1 = 0.f, t2 = 0.f, t3 = 0.f;
      if (t > 0) {
        #pragma unroll
        for (int q = 0; q < KSPLIT; q += 4) {
          float2 p0 = *(const float2*)&partial[(size_t)(q + 0) * BH + o];
          float2 p1 = *(const float2*)&partial[(size_t)(q + 1) * BH + o];
          float2 p2 = *(const float2*)&partial[(size_t)(q + 2) * BH + o];
          float2 p3 = *(const float2*)&partial[(size_t)(q + 3) * BH + o];
          s0 += p0.x; t0 += p0.y; s1 += p1.x; t1 += p1.y;
          s2 += p2.x; t2 += p2.y; s3 += p3.x; t3 += p3.y;
        }
      }
      const float sumx = (s0 + s1) + (s2 + s3);
      const float sumy = (t0 + t1) + (t2 + t3);
      float2 xin = *(const float2*)&out[(size_t)t * BH + o];
      float hpx = 0.f, hpy = 0.f;
      if (t > 0) {
        float2 hp = *(const float2*)&out[(size_t)(t - 1) * BH + o];
        hpx = hp.x; hpy = hp.y;
      }
      const float hn0 = fmaxf(xin.x + sumx, 0.f);
      const float hn1 = fmaxf(xin.y + sumy, 0.f);
      float2 r = make_float2(0.99f * hpx + 0.01f * hn0,
                             0.99f * hpy + 0.01f * hn1);
      *(float2*)&out[(size_t)t * BH + o] = r;
    }
    gbarrier(bar, ++phase, bid);
  }

  // ---- h_last = out[T-1] copied to tail of d_out ----
  {
    const size_t o = (size_t)bid * 512 + (size_t)tid * 2;
    *(float2*)&out[(size_t)T_DIM * BH + o] =
        *(const float2*)&out[(size_t)(T_DIM - 1) * BH + o];
  }
}

// =====================================================================
extern "C" void kernel_launch(void* const* d_in, const int* in_sizes, int n_in,
                              void* d_out, int out_size, void* d_ws, size_t ws_size,
                              hipStream_t stream) {
  const float* x    = (const float*)d_in[0];
  const float* Wih  = (const float*)d_in[1];
  const float* bih  = (const float*)d_in[2];
  const float* Whh  = (const float*)d_in[3];
  const float* bhh  = (const float*)d_in[4];
  float* out = (float*)d_out;

  unsigned* bar  = (unsigned*)d_ws;
  float* partial = (float*)((char*)d_ws + 4096);
  // needs 4096 + 32*131072*4 = ~16.8 MB of workspace

  hipMemsetAsync(d_ws, 0, 4096, stream);  // reset barrier counters every call

  xin_gemm<<<dim3(2048), dim3(256), 0, stream>>>(x, Wih, bih, bhh, out);
  ctrnn_scan<<<dim3(NBLK), dim3(256), 0, stream>>>(Whh, out, partial, bar);
}

// Round 2
// 16129.475 us; speedup vs baseline: 1.2013x; 1.2013x over previous
//
#include <hip/hip_runtime.h>

// Problem dims (fixed by setup_inputs): T=256, B=64, I=512, H=2048
#define T_DIM 256
#define B_DIM 64
#define I_DIM 512
#define H_DIM 2048
#define BH (B_DIM * H_DIM)      // 131072 floats per timestep slice
#define NBLK 256                // persistent-kernel grid (1 block per CU)
#define KG 16                   // k-groups (k_range 128)
#define NG 16                   // n-groups (n_range 128)

// =====================================================================
// Kernel A: xin[m,n] = sum_k x[m,k] * W_ih[n,k] + b_ih[n] + b_hh[n]
// M = T*B = 16384, K = 512, N = 2048.  Tile 128x128, BK=16, 8x8/thread.
// Writes into d_out[0 : T*B*H] (out slice t doubles as xin_t storage).
// =====================================================================
__global__ __launch_bounds__(256) void xin_gemm(
    const float* __restrict__ x, const float* __restrict__ Wih,
    const float* __restrict__ bih, const float* __restrict__ bhh,
    float* __restrict__ out)
{
  __shared__ __align__(16) float As[16][132];
  __shared__ __align__(16) float Bs[16][132];
  const int tid = threadIdx.x;
  const int nb = blockIdx.x & 15, mb = blockIdx.x >> 4;
  const int m0 = mb * 128, n0 = nb * 128;
  const int tx = tid & 15, ty = tid >> 4;

  float acc[8][8];
  #pragma unroll
  for (int i = 0; i < 8; ++i)
    #pragma unroll
    for (int j = 0; j < 8; ++j) acc[i][j] = 0.f;

  for (int k0 = 0; k0 < I_DIM; k0 += 16) {
    __syncthreads();
    {
      const int r = tid >> 1;
      #pragma unroll
      for (int c = 0; c < 2; ++c) {
        const int kq = (tid & 1) * 4 + c * 8;
        float4 va = *(const float4*)&x[(size_t)(m0 + r) * I_DIM + k0 + kq];
        As[kq + 0][r] = va.x; As[kq + 1][r] = va.y;
        As[kq + 2][r] = va.z; As[kq + 3][r] = va.w;
        float4 vb = *(const float4*)&Wih[(size_t)(n0 + r) * I_DIM + k0 + kq];
        Bs[kq + 0][r] = vb.x; Bs[kq + 1][r] = vb.y;
        Bs[kq + 2][r] = vb.z; Bs[kq + 3][r] = vb.w;
      }
    }
    __syncthreads();
    #pragma unroll 4
    for (int k = 0; k < 16; ++k) {
      float a[8], b[8];
      *(float4*)&a[0] = *(const float4*)&As[k][ty * 8];
      *(float4*)&a[4] = *(const float4*)&As[k][ty * 8 + 4];
      *(float4*)&b[0] = *(const float4*)&Bs[k][tx * 4];
      *(float4*)&b[4] = *(const float4*)&Bs[k][64 + tx * 4];
      #pragma unroll
      for (int i = 0; i < 8; ++i)
        #pragma unroll
        for (int j = 0; j < 8; ++j) acc[i][j] += a[i] * b[j];
    }
  }

  float bb[8];
  #pragma unroll
  for (int j = 0; j < 4; ++j) {
    bb[j]     = bih[n0 + tx * 4 + j]      + bhh[n0 + tx * 4 + j];
    bb[4 + j] = bih[n0 + 64 + tx * 4 + j] + bhh[n0 + 64 + tx * 4 + j];
  }
  #pragma unroll
  for (int i = 0; i < 8; ++i) {
    const size_t m = (size_t)(m0 + ty * 8 + i);
    float4 v0 = make_float4(acc[i][0] + bb[0], acc[i][1] + bb[1],
                            acc[i][2] + bb[2], acc[i][3] + bb[3]);
    float4 v1 = make_float4(acc[i][4] + bb[4], acc[i][5] + bb[5],
                            acc[i][6] + bb[6], acc[i][7] + bb[7]);
    *(float4*)&out[m * H_DIM + n0 + tx * 4]      = v0;
    *(float4*)&out[m * H_DIM + n0 + 64 + tx * 4] = v1;
  }
}

// =====================================================================
// Grid barrier, distributed slots, minimal fences:
//   bar[0]                 master flag (phase counter)
//   bar[64 + bid*16]       per-block arrival slot (64 B apart)
// Each block: ONE release fence, relaxed slot store. Block 0: 256 threads
// relaxed-poll 256 slots (no invalidates), then relaxed-store flag.
// All blocks: relaxed-poll flag, then ONE acquire fence.
// =====================================================================
__device__ __forceinline__ void gbarrier(unsigned* bar, unsigned ph, int bid) {
  __syncthreads();  // all waves' stores complete (vmcnt drained at barrier)
  __builtin_amdgcn_fence(__ATOMIC_RELEASE, "agent");  // wb L2 once per block
  if (threadIdx.x == 0)
    __hip_atomic_store(bar + 64 + bid * 16, ph, __ATOMIC_RELAXED,
                       __HIP_MEMORY_SCOPE_AGENT);
  if (bid == 0) {
    // thread i waits for block i's slot (relaxed: no cache maintenance)
    while (__hip_atomic_load(bar + 64 + threadIdx.x * 16, __ATOMIC_RELAXED,
                             __HIP_MEMORY_SCOPE_AGENT) < ph)
      __builtin_amdgcn_s_sleep(1);
    __syncthreads();
    if (threadIdx.x == 0)
      __hip_atomic_store(bar, ph, __ATOMIC_RELAXED, __HIP_MEMORY_SCOPE_AGENT);
  }
  if (threadIdx.x == 0) {
    while (__hip_atomic_load(bar, __ATOMIC_RELAXED,
                             __HIP_MEMORY_SCOPE_AGENT) < ph)
      __builtin_amdgcn_s_sleep(1);
  }
  __syncthreads();
  __builtin_amdgcn_fence(__ATOMIC_ACQUIRE, "agent");  // inv once per wave
}

// =====================================================================
// Kernel B: persistent scan.  grid = 256 blocks x 256 thr, 1 block/CU.
// Block (ng, kg): ng = n-group of 128 cols, kg = k-group of 128.
// W_hh slice (128n x 128k, 64 KB) lives in LDS for all 256 steps.
// Step t: phaseA: partial[kg][b][n0:n0+128] += h[t-1][b, k0:k0+128] @ W^T
//         barrier
//         phaseB: h[t] = 0.99*h[t-1] + 0.01*relu(xin + sum_kg partial)
//         barrier
// h history lives in d_out (in-place over xin).
// =====================================================================
__global__ __launch_bounds__(256) void ctrnn_scan(
    const float* __restrict__ Whh, float* out,
    float* __restrict__ partial, unsigned* bar)
{
  __shared__ __align__(16) float Ws[128][132];  // [k][n], 67.6 KB
  __shared__ __align__(16) float hs[128][68];   // [k][b], 34.8 KB

  const int tid = threadIdx.x;
  const int bid = blockIdx.x;
  const int ng = bid >> 4;             // 0..15
  const int kg = bid & (KG - 1);       // 0..15
  const int n0 = ng * 128, k0 = kg * 128;
  const int tn = tid & 31, tb = tid >> 5;  // tn: 32 n-quads, tb: 8 b-octets

  // ---- load W_hh slice once: W[n0+n][k0+k] -> Ws[k][n] ----
  #pragma unroll
  for (int pass = 0; pass < 16; ++pass) {
    const int n  = tid >> 1;
    const int kq = (tid & 1) * 4 + pass * 8;
    float4 w = *(const float4*)&Whh[(size_t)(n0 + n) * H_DIM + k0 + kq];
    Ws[kq + 0][n] = w.x; Ws[kq + 1][n] = w.y;
    Ws[kq + 2][n] = w.z; Ws[kq + 3][n] = w.w;
  }
  __syncthreads();

  unsigned phase = 0;
  for (int t = 0; t < T_DIM; ++t) {
    // -------- phase A: partial GEMM (skip at t=0, h_{-1}=0) --------
    if (t > 0) {
      const float* hprev = out + (size_t)(t - 1) * BH;
      #pragma unroll
      for (int c = 0; c < 8; ++c) {              // stage h -> hs[k][b]
        const int b  = tid >> 2;
        const int kq = (tid & 3) * 4 + c * 16;
        float4 h4 = *(const float4*)&hprev[(size_t)b * H_DIM + k0 + kq];
        hs[kq + 0][b] = h4.x; hs[kq + 1][b] = h4.y;
        hs[kq + 2][b] = h4.z; hs[kq + 3][b] = h4.w;
      }
      __syncthreads();

      float acc[8][4];
      #pragma unroll
      for (int i = 0; i < 8; ++i)
        #pragma unroll
        for (int j = 0; j < 4; ++j) acc[i][j] = 0.f;

      #pragma unroll 4
      for (int k = 0; k < 128; ++k) {
        float a[8], w[4];
        *(float4*)&a[0] = *(const float4*)&hs[k][tb * 8];
        *(float4*)&a[4] = *(const float4*)&hs[k][tb * 8 + 4];
        *(float4*)&w[0] = *(const float4*)&Ws[k][tn * 4];
        #pragma unroll
        for (int i = 0; i < 8; ++i)
          #pragma unroll
          for (int j = 0; j < 4; ++j) acc[i][j] += a[i] * w[j];
      }

      float* pp = partial + (size_t)kg * BH;
      #pragma unroll
      for (int i = 0; i < 8; ++i) {
        const size_t b = (size_t)(tb * 8 + i);
        *(float4*)&pp[b * H_DIM + n0 + tn * 4] =
            make_float4(acc[i][0], acc[i][1], acc[i][2], acc[i][3]);
      }
      __syncthreads();  // hs stable until all waves done (reloaded next step)
    }
    gbarrier(bar, ++phase, bid);

    // -------- phase B: reduce + leaky-relu update (in place) --------
    {
      const size_t o = (size_t)bid * 512 + (size_t)tid * 2;
      float sx = 0.f, sy = 0.f;
      if (t > 0) {
        float2 p[KG];
        #pragma unroll
        for (int q = 0; q < KG; ++q)
          p[q] = *(const float2*)&partial[(size_t)q * BH + o];
        #pragma unroll
        for (int q = 0; q < KG; ++q) { sx += p[q].x; sy += p[q].y; }
      }
      float2 xin = *(const float2*)&out[(size_t)t * BH + o];
      float hpx = 0.f, hpy = 0.f;
      if (t > 0) {
        float2 hp = *(const float2*)&out[(size_t)(t - 1) * BH + o];
        hpx = hp.x; hpy = hp.y;
      }
      const float hn0 = fmaxf(xin.x + sx, 0.f);
      const float hn1 = fmaxf(xin.y + sy, 0.f);
      float2 r = make_float2(0.99f * hpx + 0.01f * hn0,
                             0.99f * hpy + 0.01f * hn1);
      *(float2*)&out[(size_t)t * BH + o] = r;
    }
    gbarrier(bar, ++phase, bid);
  }

  // ---- h_last = out[T-1] copied to tail of d_out ----
  {
    const size_t o = (size_t)bid * 512 + (size_t)tid * 2;
    *(float2*)&out[(size_t)T_DIM * BH + o] =
        *(const float2*)&out[(size_t)(T_DIM - 1) * BH + o];
  }
}

// =====================================================================
extern "C" void kernel_launch(void* const* d_in, const int* in_sizes, int n_in,
                              void* d_out, int out_size, void* d_ws, size_t ws_size,
                              hipStream_t stream) {
  const float* x    = (const float*)d_in[0];
  const float* Wih  = (const float*)d_in[1];
  const float* bih  = (const float*)d_in[2];
  const float* Whh  = (const float*)d_in[3];
  const float* bhh  = (const float*)d_in[4];
  float* out = (float*)d_out;

  unsigned* bar  = (unsigned*)d_ws;
  float* partial = (float*)((char*)d_ws + 32768);
  // workspace: 32 KB barrier region + 16*131072*4 = ~8.4 MB partials

  hipMemsetAsync(d_ws, 0, 32768, stream);  // reset barrier slots every call

  xin_gemm<<<dim3(2048), dim3(256), 0, stream>>>(x, Wih, bih, bhh, out);
  ctrnn_scan<<<dim3(NBLK), dim3(256), 0, stream>>>(Whh, out, partial, bar);
}

// Round 3
// 6019.071 us; speedup vs baseline: 3.2192x; 2.6797x over previous
//
#include <hip/hip_runtime.h>

// Problem dims (fixed by setup_inputs): T=256, B=64, I=512, H=2048
#define T_DIM 256
#define B_DIM 64
#define I_DIM 512
#define H_DIM 2048
#define BH (B_DIM * H_DIM)      // 131072 floats per timestep slice
#define KG 32                   // k-groups (k-range 64)
#define NG 8                    // n-groups (n-range 256)

// =====================================================================
// Kernel A: xin[m,n] = sum_k x[m,k] * W_ih[n,k] + b_ih[n] + b_hh[n]
// M = T*B = 16384, K = 512, N = 2048.  Tile 128x128, BK=16, 8x8/thread.
// Rows m<64 are t=0: fold the first recurrence step (h_{-1}=0):
//   out[0] = 0.01 * relu(xin[0]).
// =====================================================================
__global__ __launch_bounds__(256) void xin_gemm(
    const float* __restrict__ x, const float* __restrict__ Wih,
    const float* __restrict__ bih, const float* __restrict__ bhh,
    float* __restrict__ out)
{
  __shared__ __align__(16) float As[16][132];
  __shared__ __align__(16) float Bs[16][132];
  const int tid = threadIdx.x;
  const int nb = blockIdx.x & 15, mb = blockIdx.x >> 4;
  const int m0 = mb * 128, n0 = nb * 128;
  const int tx = tid & 15, ty = tid >> 4;

  float acc[8][8];
  #pragma unroll
  for (int i = 0; i < 8; ++i)
    #pragma unroll
    for (int j = 0; j < 8; ++j) acc[i][j] = 0.f;

  for (int k0 = 0; k0 < I_DIM; k0 += 16) {
    __syncthreads();
    {
      const int r = tid >> 1;
      #pragma unroll
      for (int c = 0; c < 2; ++c) {
        const int kq = (tid & 1) * 4 + c * 8;
        float4 va = *(const float4*)&x[(size_t)(m0 + r) * I_DIM + k0 + kq];
        As[kq + 0][r] = va.x; As[kq + 1][r] = va.y;
        As[kq + 2][r] = va.z; As[kq + 3][r] = va.w;
        float4 vb = *(const float4*)&Wih[(size_t)(n0 + r) * I_DIM + k0 + kq];
        Bs[kq + 0][r] = vb.x; Bs[kq + 1][r] = vb.y;
        Bs[kq + 2][r] = vb.z; Bs[kq + 3][r] = vb.w;
      }
    }
    __syncthreads();
    #pragma unroll 4
    for (int k = 0; k < 16; ++k) {
      float a[8], b[8];
      *(float4*)&a[0] = *(const float4*)&As[k][ty * 8];
      *(float4*)&a[4] = *(const float4*)&As[k][ty * 8 + 4];
      *(float4*)&b[0] = *(const float4*)&Bs[k][tx * 4];
      *(float4*)&b[4] = *(const float4*)&Bs[k][64 + tx * 4];
      #pragma unroll
      for (int i = 0; i < 8; ++i)
        #pragma unroll
        for (int j = 0; j < 8; ++j) acc[i][j] += a[i] * b[j];
    }
  }

  float bb[8];
  #pragma unroll
  for (int j = 0; j < 4; ++j) {
    bb[j]     = bih[n0 + tx * 4 + j]      + bhh[n0 + tx * 4 + j];
    bb[4 + j] = bih[n0 + 64 + tx * 4 + j] + bhh[n0 + 64 + tx * 4 + j];
  }
  #pragma unroll
  for (int i = 0; i < 8; ++i) {
    const int m = m0 + ty * 8 + i;
    float v[8];
    #pragma unroll
    for (int j = 0; j < 8; ++j) v[j] = acc[i][j] + bb[j];
    if (m < B_DIM) {           // t == 0 rows: h[0] = 0.01*relu(xin)
      #pragma unroll
      for (int j = 0; j < 8; ++j) v[j] = 0.01f * fmaxf(v[j], 0.f);
    }
    *(float4*)&out[(size_t)m * H_DIM + n0 + tx * 4] =
        make_float4(v[0], v[1], v[2], v[3]);
    *(float4*)&out[(size_t)m * H_DIM + n0 + 64 + tx * 4] =
        make_float4(v[4], v[5], v[6], v[7]);
  }
}

// =====================================================================
// partial_k (per step t): partial[kg][b][n0:n0+256] =
//     h[t-1][b, k0:k0+64] @ W_hh[n0:n0+256, k0:k0+64]^T
// grid 256 = NG(8) x KG(32).  256 thr, 8x8 acc per thread (64b x 256n tile).
// LDS: Ws 64x260 (66.6 KB) + hs 64x68 (17.4 KB) -> 1 block/CU.
// Per k: 4 ds_read_b128 + 64 FMA  (LDS-BW == FMA == ~128 cy/CU, balanced).
// =====================================================================
__global__ __launch_bounds__(256) void partial_k(
    const float* __restrict__ Whh, const float* __restrict__ hprev,
    float* __restrict__ partial)
{
  __shared__ __align__(16) float Ws[64][260];  // [k][n]
  __shared__ __align__(16) float hs[64][68];   // [k][b]

  const int tid = threadIdx.x, bid = blockIdx.x;
  const int kg = bid & (KG - 1), ng = bid >> 5;
  const int n0 = ng * 256, k0 = kg * 64;

  // stage W: lane = n-row (coalesced across passes via L1 line reuse);
  // LDS writes lane-consecutive in n -> conflict-free.
  #pragma unroll
  for (int pass = 0; pass < 16; ++pass) {
    const int kq = pass * 4;
    float4 w = *(const float4*)&Whh[(size_t)(n0 + tid) * H_DIM + k0 + kq];
    Ws[kq + 0][tid] = w.x; Ws[kq + 1][tid] = w.y;
    Ws[kq + 2][tid] = w.z; Ws[kq + 3][tid] = w.w;
  }
  // stage h: b = tid&63, q = tid>>6; kq = q*16 + pass*4 (L1 line reuse).
  {
    const int b = tid & 63, q = tid >> 6;
    #pragma unroll
    for (int pass = 0; pass < 4; ++pass) {
      const int kq = q * 16 + pass * 4;
      float4 h4 = *(const float4*)&hprev[(size_t)b * H_DIM + k0 + kq];
      hs[kq + 0][b] = h4.x; hs[kq + 1][b] = h4.y;
      hs[kq + 2][b] = h4.z; hs[kq + 3][b] = h4.w;
    }
  }
  __syncthreads();

  const int tn = tid & 31, tb = tid >> 5;
  float acc[8][8];
  #pragma unroll
  for (int i = 0; i < 8; ++i)
    #pragma unroll
    for (int j = 0; j < 8; ++j) acc[i][j] = 0.f;

  #pragma unroll 4
  for (int k = 0; k < 64; ++k) {
    float a[8], w[8];
    *(float4*)&a[0] = *(const float4*)&hs[k][tb * 8];
    *(float4*)&a[4] = *(const float4*)&hs[k][tb * 8 + 4];
    *(float4*)&w[0] = *(const float4*)&Ws[k][tn * 4];
    *(float4*)&w[4] = *(const float4*)&Ws[k][128 + tn * 4];
    #pragma unroll
    for (int i = 0; i < 8; ++i)
      #pragma unroll
      for (int j = 0; j < 8; ++j) acc[i][j] += a[i] * w[j];
  }

  float* pp = partial + (size_t)kg * BH;
  #pragma unroll
  for (int i = 0; i < 8; ++i) {
    const size_t b = (size_t)(tb * 8 + i);
    *(float4*)&pp[b * H_DIM + n0 + tn * 4] =
        make_float4(acc[i][0], acc[i][1], acc[i][2], acc[i][3]);
    *(float4*)&pp[b * H_DIM + n0 + 128 + tn * 4] =
        make_float4(acc[i][4], acc[i][5], acc[i][6], acc[i][7]);
  }
}

// =====================================================================
// reduce_k (per step t>=1): h[t] = 0.99*h[t-1] + 0.01*relu(xin + sum partial)
// In place over out[t] (xin slice).  t==T-1 also writes h_last tail.
// =====================================================================
__global__ __launch_bounds__(256) void reduce_k(
    const float* __restrict__ partial, float* __restrict__ out, const int t)
{
  const size_t o = (size_t)blockIdx.x * 512 + (size_t)threadIdx.x * 2;
  float sx = 0.f, sy = 0.f;
  #pragma unroll
  for (int q = 0; q < KG; ++q) {
    float2 p = *(const float2*)&partial[(size_t)q * BH + o];
    sx += p.x; sy += p.y;
  }
  float2 xin = *(const float2*)&out[(size_t)t * BH + o];
  float2 hp  = *(const float2*)&out[(size_t)(t - 1) * BH + o];
  float2 r = make_float2(0.99f * hp.x + 0.01f * fmaxf(xin.x + sx, 0.f),
                         0.99f * hp.y + 0.01f * fmaxf(xin.y + sy, 0.f));
  *(float2*)&out[(size_t)t * BH + o] = r;
  if (t == T_DIM - 1)
    *(float2*)&out[(size_t)T_DIM * BH + o] = r;   // h_last
}

// =====================================================================
extern "C" void kernel_launch(void* const* d_in, const int* in_sizes, int n_in,
                              void* d_out, int out_size, void* d_ws, size_t ws_size,
                              hipStream_t stream) {
  const float* x    = (const float*)d_in[0];
  const float* Wih  = (const float*)d_in[1];
  const float* bih  = (const float*)d_in[2];
  const float* Whh  = (const float*)d_in[3];
  const float* bhh  = (const float*)d_in[4];
  float* out = (float*)d_out;

  float* partial = (float*)d_ws;   // KG * BH * 4 = 16.8 MB

  xin_gemm<<<dim3(2048), dim3(256), 0, stream>>>(x, Wih, bih, bhh, out);
  for (int t = 1; t < T_DIM; ++t) {
    partial_k<<<dim3(256), dim3(256), 0, stream>>>(
        Whh, out + (size_t)(t - 1) * BH, partial);
    reduce_k<<<dim3(256), dim3(256), 0, stream>>>(partial, out, t);
  }
}

// Round 4
// 5827.818 us; speedup vs baseline: 3.3248x; 1.0328x over previous
//
#include <hip/hip_runtime.h>

// Problem dims (fixed by setup_inputs): T=256, B=64, I=512, H=2048
#define T_DIM 256
#define B_DIM 64
#define I_DIM 512
#define H_DIM 2048
#define BH (B_DIM * H_DIM)      // 131072 floats per timestep slice
#define NBLK 256                // persistent grid: 1 block per CU (84KB LDS)
#define KG 32                   // k-groups (k-range 64)
#define NG 8                    // n-groups (n-range 256)

// ---------------------------------------------------------------------
// Agent-scope (device-coherent) 8B load/store: plain global ld/st with
// coherence bits — full BW, bypasses the non-cross-XCD-coherent L2 path.
// ---------------------------------------------------------------------
__device__ __forceinline__ unsigned long long aload(const float* p) {
  return __hip_atomic_load((const unsigned long long*)p, __ATOMIC_RELAXED,
                           __HIP_MEMORY_SCOPE_AGENT);
}
__device__ __forceinline__ void astore(float* p, float a, float b) {
  union { unsigned long long u; float2 f; } c; c.f = make_float2(a, b);
  __hip_atomic_store((unsigned long long*)p, c.u, __ATOMIC_RELAXED,
                     __HIP_MEMORY_SCOPE_AGENT);
}
__device__ __forceinline__ float2 u2f(unsigned long long u) {
  union { unsigned long long u; float2 f; } c; c.u = u; return c.f;
}

// =====================================================================
// Kernel A: xin[m,n] = x @ W_ih^T + b_ih + b_hh  (rows m<64 fold t=0:
// out[0] = 0.01*relu(xin[0]), h_{-1}=0).  Unchanged from R3.
// =====================================================================
__global__ __launch_bounds__(256) void xin_gemm(
    const float* __restrict__ x, const float* __restrict__ Wih,
    const float* __restrict__ bih, const float* __restrict__ bhh,
    float* __restrict__ out)
{
  __shared__ __align__(16) float As[16][132];
  __shared__ __align__(16) float Bs[16][132];
  const int tid = threadIdx.x;
  const int nb = blockIdx.x & 15, mb = blockIdx.x >> 4;
  const int m0 = mb * 128, n0 = nb * 128;
  const int tx = tid & 15, ty = tid >> 4;

  float acc[8][8];
  #pragma unroll
  for (int i = 0; i < 8; ++i)
    #pragma unroll
    for (int j = 0; j < 8; ++j) acc[i][j] = 0.f;

  for (int k0 = 0; k0 < I_DIM; k0 += 16) {
    __syncthreads();
    {
      const int r = tid >> 1;
      #pragma unroll
      for (int c = 0; c < 2; ++c) {
        const int kq = (tid & 1) * 4 + c * 8;
        float4 va = *(const float4*)&x[(size_t)(m0 + r) * I_DIM + k0 + kq];
        As[kq + 0][r] = va.x; As[kq + 1][r] = va.y;
        As[kq + 2][r] = va.z; As[kq + 3][r] = va.w;
        float4 vb = *(const float4*)&Wih[(size_t)(n0 + r) * I_DIM + k0 + kq];
        Bs[kq + 0][r] = vb.x; Bs[kq + 1][r] = vb.y;
        Bs[kq + 2][r] = vb.z; Bs[kq + 3][r] = vb.w;
      }
    }
    __syncthreads();
    #pragma unroll 4
    for (int k = 0; k < 16; ++k) {
      float a[8], b[8];
      *(float4*)&a[0] = *(const float4*)&As[k][ty * 8];
      *(float4*)&a[4] = *(const float4*)&As[k][ty * 8 + 4];
      *(float4*)&b[0] = *(const float4*)&Bs[k][tx * 4];
      *(float4*)&b[4] = *(const float4*)&Bs[k][64 + tx * 4];
      #pragma unroll
      for (int i = 0; i < 8; ++i)
        #pragma unroll
        for (int j = 0; j < 8; ++j) acc[i][j] += a[i] * b[j];
    }
  }

  float bb[8];
  #pragma unroll
  for (int j = 0; j < 4; ++j) {
    bb[j]     = bih[n0 + tx * 4 + j]      + bhh[n0 + tx * 4 + j];
    bb[4 + j] = bih[n0 + 64 + tx * 4 + j] + bhh[n0 + 64 + tx * 4 + j];
  }
  #pragma unroll
  for (int i = 0; i < 8; ++i) {
    const int m = m0 + ty * 8 + i;
    float v[8];
    #pragma unroll
    for (int j = 0; j < 8; ++j) v[j] = acc[i][j] + bb[j];
    if (m < B_DIM) {           // t == 0 rows: h[0] = 0.01*relu(xin)
      #pragma unroll
      for (int j = 0; j < 8; ++j) v[j] = 0.01f * fmaxf(v[j], 0.f);
    }
    *(float4*)&out[(size_t)m * H_DIM + n0 + tx * 4] =
        make_float4(v[0], v[1], v[2], v[3]);
    *(float4*)&out[(size_t)m * H_DIM + n0 + 64 + tx * 4] =
        make_float4(v[4], v[5], v[6], v[7]);
  }
}

// ---------------------------------------------------------------------
// Fence-free grid barrier. slots[bid*16] is each block's monotonic phase
// slot (64B apart). Arrival: explicit vmcnt drain (orders BOTH my data
// stores and my in-flight reads vs the signal) -> thread0 stores slot.
// Wait: thread i polls block i's slot (one MALL hop, no RMW, no fences).
// Bounded spin guarantees termination.
// =====================================================================
__device__ __forceinline__ void gbar(unsigned* slots, unsigned m, int bid) {
  asm volatile("s_waitcnt vmcnt(0) lgkmcnt(0)" ::: "memory");
  __syncthreads();
  if (threadIdx.x == 0)
    __hip_atomic_store(slots + (size_t)bid * 16, m, __ATOMIC_RELAXED,
                       __HIP_MEMORY_SCOPE_AGENT);
  unsigned* myslot = slots + (size_t)threadIdx.x * 16;
  for (int it = 0; it < (1 << 17); ++it) {
    if (__hip_atomic_load(myslot, __ATOMIC_RELAXED,
                          __HIP_MEMORY_SCOPE_AGENT) >= m)
      break;
    __builtin_amdgcn_s_sleep(2);
  }
  __syncthreads();
}

// =====================================================================
// Kernel B: persistent scan, 256 blocks x 256 thr, 1 block/CU.
// Block (kg, ng): k-slice 64 (kg), n-slice 256 (ng). W_hh slice staged
// to LDS ONCE for all 255 steps. Per step t:
//   A: stage h[t-1][64b x 64k] (agent-atomic loads) -> LDS; 8x8 fp32 GEMM;
//      agent-atomic-store partials. gbar(2t-1).
//   B: each thread owns region o=bid*512+tid*2: sum 32 partials (agent
//      loads) + xin (normal load, region-private) -> leaky-relu update of
//      register-resident h -> agent-store out[t]. gbar(2t).
// =====================================================================
__global__ __launch_bounds__(256) void ctrnn_scan(
    const float* __restrict__ Whh, float* out,
    float* __restrict__ partial, unsigned* slots)
{
  __shared__ __align__(16) float Ws[64][260];  // [k][n], 66.6 KB
  __shared__ __align__(16) float hs[64][68];   // [k][b], 17.4 KB

  const int tid = threadIdx.x, bid = blockIdx.x;
  const int kg = bid & (KG - 1), ng = bid >> 5;
  const int n0 = ng * 256, k0 = kg * 64;
  const int tn = tid & 31, tb = tid >> 5;

  // ---- stage W_hh slice ONCE (persistent; normal loads, clean data) ----
  #pragma unroll
  for (int pass = 0; pass < 16; ++pass) {
    const int kq = pass * 4;
    float4 w = *(const float4*)&Whh[(size_t)(n0 + tid) * H_DIM + k0 + kq];
    Ws[kq + 0][tid] = w.x; Ws[kq + 1][tid] = w.y;
    Ws[kq + 2][tid] = w.z; Ws[kq + 3][tid] = w.w;
  }

  // ---- register-resident h for my owned region o (from h[0]=out[0]) ----
  const size_t o = (size_t)bid * 512 + (size_t)tid * 2;
  float2 hreg = u2f(aload(&out[o]));

  for (int t = 1; t < T_DIM; ++t) {
    // -------------------- phase A --------------------
    const float* hprev = out + (size_t)(t - 1) * BH;
    {
      const int b = tid >> 2, q = tid & 3;
      #pragma unroll
      for (int i = 0; i < 8; ++i) {
        const int jp = q + i * 4;            // k-pair index 0..31
        float2 h2 = u2f(aload(&hprev[(size_t)b * H_DIM + k0 + jp * 2]));
        hs[jp * 2 + 0][b] = h2.x;
        hs[jp * 2 + 1][b] = h2.y;
      }
    }
    __syncthreads();

    float acc[8][8];
    #pragma unroll
    for (int i = 0; i < 8; ++i)
      #pragma unroll
      for (int j = 0; j < 8; ++j) acc[i][j] = 0.f;

    #pragma unroll 4
    for (int k = 0; k < 64; ++k) {
      float a[8], w[8];
      *(float4*)&a[0] = *(const float4*)&hs[k][tb * 8];
      *(float4*)&a[4] = *(const float4*)&hs[k][tb * 8 + 4];
      *(float4*)&w[0] = *(const float4*)&Ws[k][tn * 4];
      *(float4*)&w[4] = *(const float4*)&Ws[k][128 + tn * 4];
      #pragma unroll
      for (int i = 0; i < 8; ++i)
        #pragma unroll
        for (int j = 0; j < 8; ++j) acc[i][j] += a[i] * w[j];
    }

    {
      float* pp = partial + (size_t)kg * BH;
      #pragma unroll
      for (int i = 0; i < 8; ++i) {
        float* row = pp + (size_t)(tb * 8 + i) * H_DIM + n0;
        astore(row + tn * 4 + 0,       acc[i][0], acc[i][1]);
        astore(row + tn * 4 + 2,       acc[i][2], acc[i][3]);
        astore(row + 128 + tn * 4 + 0, acc[i][4], acc[i][5]);
        astore(row + 128 + tn * 4 + 2, acc[i][6], acc[i][7]);
      }
    }
    gbar(slots, 2 * t - 1, bid);

    // -------------------- phase B --------------------
    {
      float sx = 0.f, sy = 0.f;
      #pragma unroll
      for (int q = 0; q < KG; ++q) {
        float2 p = u2f(aload(&partial[(size_t)q * BH + o]));
        sx += p.x; sy += p.y;
      }
      float2 xin = *(const float2*)&out[(size_t)t * BH + o];  // region-private
      hreg.x = 0.99f * hreg.x + 0.01f * fmaxf(xin.x + sx, 0.f);
      hreg.y = 0.99f * hreg.y + 0.01f * fmaxf(xin.y + sy, 0.f);
      astore(&out[(size_t)t * BH + o], hreg.x, hreg.y);
      if (t == T_DIM - 1)
        astore(&out[(size_t)T_DIM * BH + o], hreg.x, hreg.y);  // h_last
    }
    gbar(slots, 2 * t, bid);
  }
}

// =====================================================================
extern "C" void kernel_launch(void* const* d_in, const int* in_sizes, int n_in,
                              void* d_out, int out_size, void* d_ws, size_t ws_size,
                              hipStream_t stream) {
  const float* x    = (const float*)d_in[0];
  const float* Wih  = (const float*)d_in[1];
  const float* bih  = (const float*)d_in[2];
  const float* Whh  = (const float*)d_in[3];
  const float* bhh  = (const float*)d_in[4];
  float* out = (float*)d_out;

  unsigned* slots = (unsigned*)d_ws;                    // 256 * 64B = 16 KB
  float* partial  = (float*)((char*)d_ws + 32768);      // KG*BH*4 = 16.8 MB

  hipMemsetAsync(d_ws, 0, 32768, stream);  // reset barrier slots every call

  xin_gemm<<<dim3(2048), dim3(256), 0, stream>>>(x, Wih, bih, bhh, out);
  ctrnn_scan<<<dim3(NBLK), dim3(256), 0, stream>>>(Whh, out, partial, slots);
}

// Round 5
// 4456.315 us; speedup vs baseline: 4.3481x; 1.3078x over previous
//
#include <hip/hip_runtime.h>

// Problem dims (fixed by setup_inputs): T=256, B=64, I=512, H=2048
#define T_DIM 256
#define B_DIM 64
#define I_DIM 512
#define H_DIM 2048
#define BH (B_DIM * H_DIM)      // 131072 floats per timestep slice
#define NBLK 256                // persistent grid: 1 block per CU
#define KG 8                    // k-groups (k-range 256)
#define NG 32                   // n-groups (n-range 64)
#define KR 256                  // k_range per block
#define KP 264                  // padded LDS row (elements) -> 528B stride

typedef __attribute__((ext_vector_type(8))) short bf16x8;
typedef __attribute__((ext_vector_type(4))) float f32x4;

// ---------------------------------------------------------------------
// Agent-scope (device-coherent) loads/stores: sc-bit global ops, full BW,
// bypass the non-cross-XCD-coherent local-L2 path. (Validated R4.)
// ---------------------------------------------------------------------
__device__ __forceinline__ float2 aload8(const float* p) {
  union { unsigned long long u; float2 f; } c;
  c.u = __hip_atomic_load((const unsigned long long*)p, __ATOMIC_RELAXED,
                          __HIP_MEMORY_SCOPE_AGENT);
  return c.f;
}
__device__ __forceinline__ void astore8(float* p, float a, float b) {
  union { unsigned long long u; float2 f; } c; c.f = make_float2(a, b);
  __hip_atomic_store((unsigned long long*)p, c.u, __ATOMIC_RELAXED,
                     __HIP_MEMORY_SCOPE_AGENT);
}
__device__ __forceinline__ void astore4(float* p, float a) {
  union { unsigned u; float f; } c; c.f = a;
  __hip_atomic_store((unsigned*)p, c.u, __ATOMIC_RELAXED,
                     __HIP_MEMORY_SCOPE_AGENT);
}

// bf16 split: hi = RNE(x), lo = RNE(x - hi).  x - (float)hi is exact.
__device__ __forceinline__ unsigned bf16_rne(float x) {
  union { float f; unsigned u; } c; c.f = x;
  return (c.u + 0x7FFFu + ((c.u >> 16) & 1u)) >> 16;
}
__device__ __forceinline__ float bf16_to_f(unsigned b) {
  union { float f; unsigned u; } c; c.u = b << 16; return c.f;
}
// convert a pair of floats (k even, k+1) -> packed u32 hi-plane & lo-plane
__device__ __forceinline__ void cvt_pair(float x0, float x1,
                                         unsigned& hi, unsigned& lo) {
  unsigned h0 = bf16_rne(x0), h1 = bf16_rne(x1);
  float r0 = x0 - bf16_to_f(h0), r1 = x1 - bf16_to_f(h1);
  unsigned l0 = bf16_rne(r0), l1 = bf16_rne(r1);
  hi = h0 | (h1 << 16);
  lo = l0 | (l1 << 16);
}

// =====================================================================
// Kernel A: xin = x @ W_ih^T + b_ih + b_hh  (rows m<64 fold t=0:
// out[0] = 0.01*relu(xin[0])).  Unchanged from R3/R4 (fp32 VALU).
// =====================================================================
__global__ __launch_bounds__(256) void xin_gemm(
    const float* __restrict__ x, const float* __restrict__ Wih,
    const float* __restrict__ bih, const float* __restrict__ bhh,
    float* __restrict__ out)
{
  __shared__ __align__(16) float As[16][132];
  __shared__ __align__(16) float Bs[16][132];
  const int tid = threadIdx.x;
  const int nb = blockIdx.x & 15, mb = blockIdx.x >> 4;
  const int m0 = mb * 128, n0 = nb * 128;
  const int tx = tid & 15, ty = tid >> 4;

  float acc[8][8];
  #pragma unroll
  for (int i = 0; i < 8; ++i)
    #pragma unroll
    for (int j = 0; j < 8; ++j) acc[i][j] = 0.f;

  for (int k0 = 0; k0 < I_DIM; k0 += 16) {
    __syncthreads();
    {
      const int r = tid >> 1;
      #pragma unroll
      for (int c = 0; c < 2; ++c) {
        const int kq = (tid & 1) * 4 + c * 8;
        float4 va = *(const float4*)&x[(size_t)(m0 + r) * I_DIM + k0 + kq];
        As[kq + 0][r] = va.x; As[kq + 1][r] = va.y;
        As[kq + 2][r] = va.z; As[kq + 3][r] = va.w;
        float4 vb = *(const float4*)&Wih[(size_t)(n0 + r) * I_DIM + k0 + kq];
        Bs[kq + 0][r] = vb.x; Bs[kq + 1][r] = vb.y;
        Bs[kq + 2][r] = vb.z; Bs[kq + 3][r] = vb.w;
      }
    }
    __syncthreads();
    #pragma unroll 4
    for (int k = 0; k < 16; ++k) {
      float a[8], b[8];
      *(float4*)&a[0] = *(const float4*)&As[k][ty * 8];
      *(float4*)&a[4] = *(const float4*)&As[k][ty * 8 + 4];
      *(float4*)&b[0] = *(const float4*)&Bs[k][tx * 4];
      *(float4*)&b[4] = *(const float4*)&Bs[k][64 + tx * 4];
      #pragma unroll
      for (int i = 0; i < 8; ++i)
        #pragma unroll
        for (int j = 0; j < 8; ++j) acc[i][j] += a[i] * b[j];
    }
  }

  float bb[8];
  #pragma unroll
  for (int j = 0; j < 4; ++j) {
    bb[j]     = bih[n0 + tx * 4 + j]      + bhh[n0 + tx * 4 + j];
    bb[4 + j] = bih[n0 + 64 + tx * 4 + j] + bhh[n0 + 64 + tx * 4 + j];
  }
  #pragma unroll
  for (int i = 0; i < 8; ++i) {
    const int m = m0 + ty * 8 + i;
    float v[8];
    #pragma unroll
    for (int j = 0; j < 8; ++j) v[j] = acc[i][j] + bb[j];
    if (m < B_DIM) {
      #pragma unroll
      for (int j = 0; j < 8; ++j) v[j] = 0.01f * fmaxf(v[j], 0.f);
    }
    *(float4*)&out[(size_t)m * H_DIM + n0 + tx * 4] =
        make_float4(v[0], v[1], v[2], v[3]);
    *(float4*)&out[(size_t)m * H_DIM + n0 + 64 + tx * 4] =
        make_float4(v[4], v[5], v[6], v[7]);
  }
}

// ---------------------------------------------------------------------
// Fence-free grid barrier (validated R4): vmcnt drain -> slot store;
// thread i polls block i's slot. Bounded spin.
// ---------------------------------------------------------------------
__device__ __forceinline__ void gbar(unsigned* slots, unsigned m, int bid) {
  asm volatile("s_waitcnt vmcnt(0) lgkmcnt(0)" ::: "memory");
  __syncthreads();
  if (threadIdx.x == 0)
    __hip_atomic_store(slots + (size_t)bid * 16, m, __ATOMIC_RELAXED,
                       __HIP_MEMORY_SCOPE_AGENT);
  unsigned* myslot = slots + (size_t)threadIdx.x * 16;
  for (int it = 0; it < (1 << 17); ++it) {
    if (__hip_atomic_load(myslot, __ATOMIC_RELAXED,
                          __HIP_MEMORY_SCOPE_AGENT) >= m)
      break;
    __builtin_amdgcn_s_sleep(2);
  }
  __syncthreads();
}

// =====================================================================
// Kernel B: persistent MFMA scan. 256 blocks x 256 thr (4 waves), 1/CU.
// Block (ng,kg): n-slice 64, k-slice 256. W slice in LDS as bf16 hi/lo
// (split-bf16: W=Whi+Wlo, h=hhi+hlo; partial = hh+hl+lh, fp32 acc).
// Per step: stage h[t-1] slice -> cvt -> LDS; 4 waves do 64x64x256 via
// mfma_f32_16x16x32_bf16 (wave = 32b x 32n = 2x2 16-tiles); astore
// partials fp32; gbar; phase B: o-region reduce KG partials + leaky-relu,
// register h; astore out[t]; gbar.
// LDS: 4 planes [64][264] short = 132 KB.
// =====================================================================
__global__ __launch_bounds__(256) void ctrnn_scan(
    const float* __restrict__ Whh, float* out,
    float* __restrict__ partial, unsigned* slots)
{
  __shared__ __align__(16) short Whi[64][KP], Wlo[64][KP];
  __shared__ __align__(16) short Hhi[64][KP], Hlo[64][KP];

  const int tid = threadIdx.x, bid = blockIdx.x;
  const int kg = bid & (KG - 1), ng = bid >> 3;
  const int n0 = ng * 64, k0 = kg * KR;

  const int lane = tid & 63, wid = tid >> 6;
  const int wb = wid & 1, wn = wid >> 1;     // wave tile: 32b x 32n
  const int fr = lane & 15, fq = lane >> 4;  // frag row / k-quarter

  // ---- stage W_hh slice ONCE: fp32 -> bf16 hi/lo planes ----
  {
    const int n = tid >> 2, kq = (tid & 3) * 64;
    #pragma unroll
    for (int i = 0; i < 16; ++i) {
      float4 w = *(const float4*)&Whh[(size_t)(n0 + n) * H_DIM + k0 + kq + i * 4];
      unsigned h0, l0, h1, l1;
      cvt_pair(w.x, w.y, h0, l0);
      cvt_pair(w.z, w.w, h1, l1);
      *(unsigned*)&Whi[n][kq + i * 4]     = h0;
      *(unsigned*)&Whi[n][kq + i * 4 + 2] = h1;
      *(unsigned*)&Wlo[n][kq + i * 4]     = l0;
      *(unsigned*)&Wlo[n][kq + i * 4 + 2] = l1;
    }
  }

  // ---- register-resident h for my owned region o ----
  const size_t o = (size_t)bid * 512 + (size_t)tid * 2;
  float2 hreg = aload8(&out[o]);

  for (int t = 1; t < T_DIM; ++t) {
    // -------------------- phase A: stage h[t-1], cvt to LDS --------------------
    const float* hprev = out + (size_t)(t - 1) * BH;
    {
      const int b = tid >> 2, kq = (tid & 3) * 64;
      #pragma unroll
      for (int i = 0; i < 32; ++i) {
        float2 h2 = aload8(&hprev[(size_t)b * H_DIM + k0 + kq + i * 2]);
        unsigned hh, ll;
        cvt_pair(h2.x, h2.y, hh, ll);
        *(unsigned*)&Hhi[b][kq + i * 2] = hh;
        *(unsigned*)&Hlo[b][kq + i * 2] = ll;
      }
    }
    __syncthreads();

    // -------------------- 64x64x256 MFMA GEMM --------------------
    f32x4 acc[2][2];
    #pragma unroll
    for (int bt = 0; bt < 2; ++bt)
      #pragma unroll
      for (int nt = 0; nt < 2; ++nt)
        acc[bt][nt] = (f32x4){0.f, 0.f, 0.f, 0.f};

    #pragma unroll 2
    for (int kc = 0; kc < KR / 32; ++kc) {
      bf16x8 ah[2], al[2], bh[2], bl[2];
      #pragma unroll
      for (int bt = 0; bt < 2; ++bt) {
        const int row = wb * 32 + bt * 16 + fr;
        ah[bt] = *(const bf16x8*)&Hhi[row][kc * 32 + fq * 8];
        al[bt] = *(const bf16x8*)&Hlo[row][kc * 32 + fq * 8];
      }
      #pragma unroll
      for (int nt = 0; nt < 2; ++nt) {
        const int row = wn * 32 + nt * 16 + fr;
        bh[nt] = *(const bf16x8*)&Whi[row][kc * 32 + fq * 8];
        bl[nt] = *(const bf16x8*)&Wlo[row][kc * 32 + fq * 8];
      }
      #pragma unroll
      for (int bt = 0; bt < 2; ++bt)
        #pragma unroll
        for (int nt = 0; nt < 2; ++nt) {
          acc[bt][nt] = __builtin_amdgcn_mfma_f32_16x16x32_bf16(
              ah[bt], bh[nt], acc[bt][nt], 0, 0, 0);
          acc[bt][nt] = __builtin_amdgcn_mfma_f32_16x16x32_bf16(
              ah[bt], bl[nt], acc[bt][nt], 0, 0, 0);
          acc[bt][nt] = __builtin_amdgcn_mfma_f32_16x16x32_bf16(
              al[bt], bh[nt], acc[bt][nt], 0, 0, 0);
        }
    }

    // store partials (C layout: n = lane&15, b = (lane>>4)*4 + reg)
    {
      float* pp = partial + (size_t)kg * BH;
      #pragma unroll
      for (int bt = 0; bt < 2; ++bt)
        #pragma unroll
        for (int nt = 0; nt < 2; ++nt) {
          const int n = n0 + wn * 32 + nt * 16 + fr;
          #pragma unroll
          for (int j = 0; j < 4; ++j) {
            const int b = wb * 32 + bt * 16 + fq * 4 + j;
            astore4(&pp[(size_t)b * H_DIM + n], acc[bt][nt][j]);
          }
        }
    }
    gbar(slots, 2 * t - 1, bid);

    // -------------------- phase B: reduce + leaky-relu --------------------
    {
      float sx = 0.f, sy = 0.f;
      #pragma unroll
      for (int q = 0; q < KG; ++q) {
        float2 p = aload8(&partial[(size_t)q * BH + o]);
        sx += p.x; sy += p.y;
      }
      float2 xin = *(const float2*)&out[(size_t)t * BH + o];  // region-private
      hreg.x = 0.99f * hreg.x + 0.01f * fmaxf(xin.x + sx, 0.f);
      hreg.y = 0.99f * hreg.y + 0.01f * fmaxf(xin.y + sy, 0.f);
      astore8(&out[(size_t)t * BH + o], hreg.x, hreg.y);
      if (t == T_DIM - 1)
        astore8(&out[(size_t)T_DIM * BH + o], hreg.x, hreg.y);  // h_last
    }
    gbar(slots, 2 * t, bid);
  }
}

// =====================================================================
extern "C" void kernel_launch(void* const* d_in, const int* in_sizes, int n_in,
                              void* d_out, int out_size, void* d_ws, size_t ws_size,
                              hipStream_t stream) {
  const float* x    = (const float*)d_in[0];
  const float* Wih  = (const float*)d_in[1];
  const float* bih  = (const float*)d_in[2];
  const float* Whh  = (const float*)d_in[3];
  const float* bhh  = (const float*)d_in[4];
  float* out = (float*)d_out;

  unsigned* slots = (unsigned*)d_ws;                    // 256 * 64B = 16 KB
  float* partial  = (float*)((char*)d_ws + 32768);      // KG*BH*4 = 4.2 MB

  hipMemsetAsync(d_ws, 0, 32768, stream);  // reset barrier slots every call

  xin_gemm<<<dim3(2048), dim3(256), 0, stream>>>(x, Wih, bih, bhh, out);
  ctrnn_scan<<<dim3(NBLK), dim3(256), 0, stream>>>(Whh, out, partial, slots);
}